// Round 4
// baseline (273.739 us; speedup 1.0000x reference)
//
#include <hip/hip_runtime.h>
#include <stdint.h>

#define B_   8
#define N_   2048
#define C_   128
#define EPS_ 0.1f

typedef __attribute__((ext_vector_type(8))) short short8;
typedef __attribute__((ext_vector_type(4))) float f32x4;

__device__ __forceinline__ unsigned short f2bf(float f) {
    union { float f; uint32_t u; } v; v.f = f;
    uint32_t u = v.u + 0x7FFF + ((v.u >> 16) & 1);   // RNE (inputs are finite)
    return (unsigned short)(u >> 16);
}

// ---------------- kernel 0: Wt[o][k] = bf16(W[k][o]) ----------------
__global__ __launch_bounds__(128) void k_wt(const float* __restrict__ W,
                                            unsigned short* __restrict__ Wt) {
    const int o = blockIdx.x, k = threadIdx.x;
    Wt[o * C_ + k] = f2bf(W[k * C_ + o]);
}

// ---- kernel 1: ht[b][o][j]=bf16(h), al/ar = h . w_att (MFMA x@W) ----
__global__ __launch_bounds__(256) void k_h(
    const float* __restrict__ x, const unsigned short* __restrict__ Wt,
    const float* __restrict__ wl, const float* __restrict__ wr,
    unsigned short* __restrict__ ht, float* __restrict__ al, float* __restrict__ ar)
{
    const int b    = blockIdx.x >> 5;
    const int i0   = (blockIdx.x & 31) * 64;
    const int t    = threadIdx.x;
    const int lane = t & 63;
    const int wid  = t >> 6;

    // [row][k] bf16, XOR-swizzled in 16B units: u' = u ^ (row&15)
    __shared__ __align__(16) unsigned short xs[64 * 128];
    __shared__ __align__(16) unsigned short ws[128 * 128];

    // stage x (fp32 -> bf16)
    #pragma unroll
    for (int p = 0; p < 4; ++p) {
        const int s = p * 256 + t, row = s >> 4, u = s & 15;
        const float* gp = x + ((size_t)(b * N_ + i0 + row) * C_ + u * 8);
        float4 f0 = *(const float4*)gp;
        float4 f1 = *(const float4*)(gp + 4);
        short8 tv;
        tv[0] = (short)f2bf(f0.x); tv[1] = (short)f2bf(f0.y);
        tv[2] = (short)f2bf(f0.z); tv[3] = (short)f2bf(f0.w);
        tv[4] = (short)f2bf(f1.x); tv[5] = (short)f2bf(f1.y);
        tv[6] = (short)f2bf(f1.z); tv[7] = (short)f2bf(f1.w);
        *(short8*)&xs[row * 128 + (u ^ (row & 15)) * 8] = tv;
    }
    // stage Wt (already bf16)
    #pragma unroll
    for (int p = 0; p < 8; ++p) {
        const int s = p * 256 + t, o = s >> 4, u = s & 15;
        int4 v = *(const int4*)(Wt + o * C_ + u * 8);
        *(int4*)&ws[o * 128 + (u ^ (o & 15)) * 8] = v;
    }
    __syncthreads();

    const int m0 = wid * 16, lr = lane & 15, q = lane >> 4;
    f32x4 acc[8];
    #pragma unroll
    for (int i = 0; i < 8; ++i) acc[i] = (f32x4){0.f, 0.f, 0.f, 0.f};

    #pragma unroll
    for (int s = 0; s < 4; ++s) {
        const int m = m0 + lr;
        short8 af = *(const short8*)&xs[m * 128 + ((s * 4 + q) ^ (m & 15)) * 8];
        #pragma unroll
        for (int tt = 0; tt < 8; ++tt) {
            const int o = tt * 16 + lr;
            short8 bf = *(const short8*)&ws[o * 128 + ((s * 4 + q) ^ (o & 15)) * 8];
            acc[tt] = __builtin_amdgcn_mfma_f32_16x16x32_bf16(af, bf, acc[tt], 0, 0, 0);
        }
    }

    // epilogue: ht (transposed bf16) + al/ar partials
    float pl[4] = {0.f, 0.f, 0.f, 0.f}, pr[4] = {0.f, 0.f, 0.f, 0.f};
    const int j0 = i0 + m0 + q * 4;     // D rows = j index, 4 consecutive
    #pragma unroll
    for (int tt = 0; tt < 8; ++tt) {
        const int o = tt * 16 + lr;
        const float wlv = wl[o], wrv = wr[o];
        unsigned int lo = (unsigned int)f2bf(acc[tt][0]) | ((unsigned int)f2bf(acc[tt][1]) << 16);
        unsigned int hi = (unsigned int)f2bf(acc[tt][2]) | ((unsigned int)f2bf(acc[tt][3]) << 16);
        uint2 u2; u2.x = lo; u2.y = hi;
        *(uint2*)&ht[((size_t)(b * C_ + o)) * N_ + j0] = u2;
        #pragma unroll
        for (int r = 0; r < 4; ++r) {
            pl[r] = fmaf(acc[tt][r], wlv, pl[r]);
            pr[r] = fmaf(acc[tt][r], wrv, pr[r]);
        }
    }
    #pragma unroll
    for (int msk = 1; msk < 16; msk <<= 1) {
        #pragma unroll
        for (int r = 0; r < 4; ++r) {
            pl[r] += __shfl_xor(pl[r], msk, 64);
            pr[r] += __shfl_xor(pr[r], msk, 64);
        }
    }
    if (lr == 0) {
        #pragma unroll
        for (int r = 0; r < 4; ++r) {
            al[b * N_ + j0 + r] = pl[r];
            ar[b * N_ + j0 + r] = pr[r];
        }
    }
}

// ---- kernel 2: out = mask(tanh(ar_i*al_j)) @ h + eps*x0  (MFMA) ----
// ZERO barriers: each wave stages alpha for ITS OWN 16 m-rows into a
// wave-private LDS transpose buffer (coalesced adj reads, in-order per-wave
// DS, lgkmcnt-only sync). ht B-fragments direct from global (L1/L2).
// adj prefetched 4 chunks deep, ht/al 2 deep -> loads stay in flight
// (no vmcnt(0) drain anywhere). 512 blocks x 256 thr, 2 blocks/CU.
struct AdjC { int4   a[4]; };    // 16 adj ints  (lane's j-range of one chunk)
struct AlC  { float4 f[4]; };    // 16 al floats
struct HbC  { int4   h[8]; };    // 8 B-fragments (s2*4+tt)

__global__ __launch_bounds__(256, 2) void k_out(
    const int* __restrict__ adj, const unsigned short* __restrict__ ht,
    const float* __restrict__ al, const float* __restrict__ ar,
    const float* __restrict__ x0, float* __restrict__ out)
{
    const int b    = blockIdx.x >> 6;
    const int i0   = (blockIdx.x & 63) * 32;
    const int t    = threadIdx.x;
    const int lane = t & 63;
    const int wid  = t >> 6;

    const int m0 = (wid & 1) * 16, n0 = (wid >> 1) * 64;

    // wave-private alpha transpose: [wave][buf][16 rows][64 j] bf16 = 16 KB
    __shared__ __align__(16) unsigned short a_s[4][2][16 * 64];
    unsigned short* wls = &a_s[wid][0][0];          // buf stride = 1024 elems

    // ---- stage-side lane mapping: row r = lane>>2, j-group g = lane&3 ----
    const int r = lane >> 2, g = lane & 3;
    const float arv = ar[b * N_ + i0 + m0 + r];
    const float tl  = 2.f * arv;
    const int*   adjp = adj + ((size_t)(b * N_) + i0 + m0 + r) * N_ + g * 16;
    const float* alp  = al + b * N_ + g * 16;

    auto ld_adj = [&](int c) -> AdjC {
        AdjC A; const int j0 = (c & 31) * 64;
        #pragma unroll
        for (int k = 0; k < 4; ++k) A.a[k] = *(const int4*)(adjp + j0 + k * 4);
        return A;
    };
    auto ld_al = [&](int c) -> AlC {
        AlC L; const int j0 = (c & 31) * 64;
        #pragma unroll
        for (int k = 0; k < 4; ++k) L.f[k] = *(const float4*)(alp + j0 + k * 4);
        return L;
    };

    auto stage = [&](int buf, const AdjC& A, const AlC& L) {
        const int*   av = (const int*)&A.a[0];
        const float* lv = (const float*)&L.f[0];
        short8 p0, p1;
        #pragma unroll
        for (int e = 0; e < 8; ++e) {
            float ex = __expf(tl * lv[e]);
            float th = 1.f - 2.f * __builtin_amdgcn_rcpf(ex + 1.f);
            p0[e] = av[e] ? (short)f2bf(th) : (short)0;
        }
        #pragma unroll
        for (int e = 0; e < 8; ++e) {
            float ex = __expf(tl * lv[8 + e]);
            float th = 1.f - 2.f * __builtin_amdgcn_rcpf(ex + 1.f);
            p1[e] = av[8 + e] ? (short)f2bf(th) : (short)0;
        }
        unsigned short* wp = wls + buf * 1024 + r * 64;
        *(short8*)&wp[((g * 2    ) ^ (r & 7)) * 8] = p0;
        *(short8*)&wp[((g * 2 + 1) ^ (r & 7)) * 8] = p1;
    };

    // ---- mma-side ----
    const int lr = lane & 15, q = lane >> 4;
    const unsigned short* hbp = ht + ((size_t)(b * C_) + n0 + lr) * N_ + q * 8;

    auto ld_hb = [&](int c) -> HbC {
        HbC H; const int j0 = (c & 31) * 64;
        #pragma unroll
        for (int s2 = 0; s2 < 2; ++s2)
            #pragma unroll
            for (int tt = 0; tt < 4; ++tt)
                H.h[s2 * 4 + tt] =
                    *(const int4*)(hbp + (size_t)(tt * 16) * N_ + j0 + s2 * 32);
        return H;
    };

    f32x4 acc[4];
    #pragma unroll
    for (int i = 0; i < 4; ++i) acc[i] = (f32x4){0.f, 0.f, 0.f, 0.f};

    auto mma = [&](int buf, const HbC& H) {
        const unsigned short* rp = wls + buf * 1024 + lr * 64;
        #pragma unroll
        for (int s2 = 0; s2 < 2; ++s2) {
            short8 afr = *(const short8*)&rp[((s2 * 4 + q) ^ (lr & 7)) * 8];
            #pragma unroll
            for (int tt = 0; tt < 4; ++tt) {
                short8 bfr = *(const short8*)&H.h[s2 * 4 + tt];
                acc[tt] = __builtin_amdgcn_mfma_f32_16x16x32_bf16(afr, bfr, acc[tt], 0, 0, 0);
            }
        }
    };

    // ---- prologue ----
    AdjC adjA, adjB, adjC_, adjD;
    AlC  alA, alB;
    HbC  hbA, hbB;
    {
        AdjC a0 = ld_adj(0); AlC l0 = ld_al(0);
        adjA = ld_adj(1); adjB = ld_adj(2); adjC_ = ld_adj(3); adjD = ld_adj(4);
        alA  = ld_al(1);  alB  = ld_al(2);
        hbA  = ld_hb(0);  hbB  = ld_hb(1);
        stage(0, a0, l0);                    // chunk 0 -> buf0
    }

    // Invariant at top of iter k (c0 = 4k): buf0 = chunk c0 staged;
    // adjA..D = chunks c0+1..c0+4; alA,alB = c0+1,c0+2; hbA,hbB = c0,c0+1.
    #pragma unroll 1
    for (int k = 0; k < 8; ++k) {
        const int c0 = k * 4;

        stage(1, adjA, alA);                         // chunk c0+1 -> buf1
        adjA = ld_adj(c0 + 5); alA = ld_al(c0 + 3);
        mma(0, hbA);                                 // chunk c0
        hbA = ld_hb(c0 + 2);

        stage(0, adjB, alB);                         // chunk c0+2 -> buf0
        adjB = ld_adj(c0 + 6); alB = ld_al(c0 + 4);
        mma(1, hbB);                                 // chunk c0+1
        hbB = ld_hb(c0 + 3);

        stage(1, adjC_, alA);                        // chunk c0+3 -> buf1
        adjC_ = ld_adj(c0 + 7); alA = ld_al(c0 + 5);
        mma(0, hbA);                                 // chunk c0+2
        hbA = ld_hb(c0 + 4);

        if (k < 7) stage(0, adjD, alB);              // chunk c0+4 -> buf0
        adjD = ld_adj(c0 + 8); alB = ld_al(c0 + 6);
        mma(1, hbB);                                 // chunk c0+3
        hbB = ld_hb(c0 + 5);
    }

    // ---- epilogue: out = acc + eps*x0 ----
    #pragma unroll
    for (int tt = 0; tt < 4; ++tt) {
        const int o = n0 + tt * 16 + lr;
        #pragma unroll
        for (int rr = 0; rr < 4; ++rr) {
            const int row = i0 + m0 + q * 4 + rr;
            const size_t idx = ((size_t)(b * N_) + row) * C_ + o;
            out[idx] = acc[tt][rr] + EPS_ * x0[idx];
        }
    }
}

extern "C" void kernel_launch(void* const* d_in, const int* in_sizes, int n_in,
                              void* d_out, int out_size, void* d_ws, size_t ws_size,
                              hipStream_t stream) {
    const float* x   = (const float*)d_in[0];
    const float* x0  = (const float*)d_in[1];
    const int*   adj = (const int*)d_in[2];
    const float* W   = (const float*)d_in[3];
    const float* wl  = (const float*)d_in[4];
    const float* wr  = (const float*)d_in[5];
    float* out = (float*)d_out;

    unsigned short* ht = (unsigned short*)d_ws;                      // 4 MB
    float* al = (float*)((char*)d_ws + (size_t)B_ * C_ * N_ * 2);
    float* ar = al + B_ * N_;
    unsigned short* Wt = (unsigned short*)(ar + B_ * N_);            // 32 KB

    k_wt <<<C_,             C_,  0, stream>>>(W, Wt);
    k_h  <<<B_ * (N_ / 64), 256, 0, stream>>>(x, Wt, wl, wr, ht, al, ar);
    k_out<<<B_ * (N_ / 32), 256, 0, stream>>>(adj, ht, al, ar, x0, out);
}

// Round 6
// 255.064 us; speedup vs baseline: 1.0732x; 1.0732x over previous
//
#include <hip/hip_runtime.h>
#include <stdint.h>

#define B_   8
#define N_   2048
#define C_   128
#define EPS_ 0.1f

typedef __attribute__((ext_vector_type(8))) short short8;
typedef __attribute__((ext_vector_type(4))) float f32x4;

__device__ __forceinline__ unsigned short f2bf(float f) {
    union { float f; uint32_t u; } v; v.f = f;
    uint32_t u = v.u + 0x7FFF + ((v.u >> 16) & 1);   // RNE (inputs are finite)
    return (unsigned short)(u >> 16);
}

// ---------------- kernel 0: Wt[o][k] = bf16(W[k][o]) ----------------
__global__ __launch_bounds__(128) void k_wt(const float* __restrict__ W,
                                            unsigned short* __restrict__ Wt) {
    const int o = blockIdx.x, k = threadIdx.x;
    Wt[o * C_ + k] = f2bf(W[k * C_ + o]);
}

// ---- kernel 1: ht[b][o][j]=bf16(h), al/ar = h . w_att (MFMA x@W) ----
__global__ __launch_bounds__(256) void k_h(
    const float* __restrict__ x, const unsigned short* __restrict__ Wt,
    const float* __restrict__ wl, const float* __restrict__ wr,
    unsigned short* __restrict__ ht, float* __restrict__ al, float* __restrict__ ar)
{
    const int b    = blockIdx.x >> 5;
    const int i0   = (blockIdx.x & 31) * 64;
    const int t    = threadIdx.x;
    const int lane = t & 63;
    const int wid  = t >> 6;

    // [row][k] bf16, XOR-swizzled in 16B units: u' = u ^ (row&15)
    __shared__ __align__(16) unsigned short xs[64 * 128];
    __shared__ __align__(16) unsigned short ws[128 * 128];

    // stage x (fp32 -> bf16)
    #pragma unroll
    for (int p = 0; p < 4; ++p) {
        const int s = p * 256 + t, row = s >> 4, u = s & 15;
        const float* gp = x + ((size_t)(b * N_ + i0 + row) * C_ + u * 8);
        float4 f0 = *(const float4*)gp;
        float4 f1 = *(const float4*)(gp + 4);
        short8 tv;
        tv[0] = (short)f2bf(f0.x); tv[1] = (short)f2bf(f0.y);
        tv[2] = (short)f2bf(f0.z); tv[3] = (short)f2bf(f0.w);
        tv[4] = (short)f2bf(f1.x); tv[5] = (short)f2bf(f1.y);
        tv[6] = (short)f2bf(f1.z); tv[7] = (short)f2bf(f1.w);
        *(short8*)&xs[row * 128 + (u ^ (row & 15)) * 8] = tv;
    }
    // stage Wt (already bf16)
    #pragma unroll
    for (int p = 0; p < 8; ++p) {
        const int s = p * 256 + t, o = s >> 4, u = s & 15;
        int4 v = *(const int4*)(Wt + o * C_ + u * 8);
        *(int4*)&ws[o * 128 + (u ^ (o & 15)) * 8] = v;
    }
    __syncthreads();

    const int m0 = wid * 16, lr = lane & 15, q = lane >> 4;
    f32x4 acc[8];
    #pragma unroll
    for (int i = 0; i < 8; ++i) acc[i] = (f32x4){0.f, 0.f, 0.f, 0.f};

    #pragma unroll
    for (int s = 0; s < 4; ++s) {
        const int m = m0 + lr;
        short8 af = *(const short8*)&xs[m * 128 + ((s * 4 + q) ^ (m & 15)) * 8];
        #pragma unroll
        for (int tt = 0; tt < 8; ++tt) {
            const int o = tt * 16 + lr;
            short8 bf = *(const short8*)&ws[o * 128 + ((s * 4 + q) ^ (o & 15)) * 8];
            acc[tt] = __builtin_amdgcn_mfma_f32_16x16x32_bf16(af, bf, acc[tt], 0, 0, 0);
        }
    }

    // epilogue: ht (transposed bf16) + al/ar partials
    float pl[4] = {0.f, 0.f, 0.f, 0.f}, pr[4] = {0.f, 0.f, 0.f, 0.f};
    const int j0 = i0 + m0 + q * 4;     // D rows = j index, 4 consecutive
    #pragma unroll
    for (int tt = 0; tt < 8; ++tt) {
        const int o = tt * 16 + lr;
        const float wlv = wl[o], wrv = wr[o];
        unsigned int lo = (unsigned int)f2bf(acc[tt][0]) | ((unsigned int)f2bf(acc[tt][1]) << 16);
        unsigned int hi = (unsigned int)f2bf(acc[tt][2]) | ((unsigned int)f2bf(acc[tt][3]) << 16);
        uint2 u2; u2.x = lo; u2.y = hi;
        *(uint2*)&ht[((size_t)(b * C_ + o)) * N_ + j0] = u2;
        #pragma unroll
        for (int r = 0; r < 4; ++r) {
            pl[r] = fmaf(acc[tt][r], wlv, pl[r]);
            pr[r] = fmaf(acc[tt][r], wrv, pr[r]);
        }
    }
    #pragma unroll
    for (int msk = 1; msk < 16; msk <<= 1) {
        #pragma unroll
        for (int r = 0; r < 4; ++r) {
            pl[r] += __shfl_xor(pl[r], msk, 64);
            pr[r] += __shfl_xor(pr[r], msk, 64);
        }
    }
    if (lr == 0) {
        #pragma unroll
        for (int r = 0; r < 4; ++r) {
            al[b * N_ + j0 + r] = pl[r];
            ar[b * N_ + j0 + r] = pr[r];
        }
    }
}

// ---- kernel 2: out = mask(tanh(ar_i*al_j)) @ h + eps*x0  (MFMA) ----
// v5: streaming-MLP design. 1024 blocks x 64 thr (one wave = one 16x128
// output tile, full C => tanh & adj done exactly ONCE). No LDS, no
// barriers, no cross-wave deps. adj/al register-prefetched 2 chunks deep
// (issue->use ~1 loop body > HBM latency); ht single-buffered from L2.
// launch_bounds(64,2) => 256-VGPR cap so the prefetch is NOT sunk.
// blockIdx: b = id&7 => each XCD owns one batch (ht[b] 512KB L2-resident).
struct AdjC { int4   a[4]; };    // [s2*2+h]: adj ints, chunk cols q*8 + s2*32 + h*4 ..
struct AlC  { float4 f[4]; };    // same layout for al
struct HbC  { int4   h[16]; };   // [s2*8+tt]: ht B-fragments

__global__ __launch_bounds__(64, 2) void k_out(
    const int* __restrict__ adj, const unsigned short* __restrict__ ht,
    const float* __restrict__ al, const float* __restrict__ ar,
    const float* __restrict__ x0, float* __restrict__ out)
{
    const int b    = blockIdx.x & 7;          // XCD-local batch
    const int i0   = (blockIdx.x >> 3) * 16;  // row tile
    const int lane = threadIdx.x;             // 0..63
    const int lr   = lane & 15, q = lane >> 4;

    const float arv = ar[b * N_ + i0 + lr];
    const float tl  = 2.f * arv;

    const int*            adjp = adj + ((size_t)(b * N_) + i0 + lr) * N_ + q * 8;
    const float*          alp  = al + b * N_ + q * 8;
    const unsigned short* htp  = ht + ((size_t)(b * C_) + lr) * N_ + q * 8;

    auto ld_adj = [&](int c) -> AdjC {
        AdjC A; const int j0 = c * 64;
        #pragma unroll
        for (int s2 = 0; s2 < 2; ++s2) {
            A.a[s2 * 2]     = *(const int4*)(adjp + j0 + s2 * 32);
            A.a[s2 * 2 + 1] = *(const int4*)(adjp + j0 + s2 * 32 + 4);
        }
        return A;
    };
    auto ld_al = [&](int c) -> AlC {
        AlC L; const int j0 = c * 64;
        #pragma unroll
        for (int s2 = 0; s2 < 2; ++s2) {
            L.f[s2 * 2]     = *(const float4*)(alp + j0 + s2 * 32);
            L.f[s2 * 2 + 1] = *(const float4*)(alp + j0 + s2 * 32 + 4);
        }
        return L;
    };
    auto ld_hb = [&](int c) -> HbC {
        HbC H; const int j0 = c * 64;
        #pragma unroll
        for (int s2 = 0; s2 < 2; ++s2)
            #pragma unroll
            for (int tt = 0; tt < 8; ++tt)
                H.h[s2 * 8 + tt] =
                    *(const int4*)(htp + (size_t)(tt * 16) * N_ + j0 + s2 * 32);
        return H;
    };

    // alpha fragment for one K=32 slab (s2): 8 masked-tanh values -> bf16x8
    auto alpha2 = [&](const AdjC& A, const AlC& L, int s2) -> short8 {
        const int*   av = (const int*)&A.a[s2 * 2];
        const float* lv = (const float*)&L.f[s2 * 2];
        short8 pk;
        #pragma unroll
        for (int e = 0; e < 8; ++e) {
            float ex = __expf(tl * lv[e]);
            float th = 1.f - 2.f * __builtin_amdgcn_rcpf(ex + 1.f);
            pk[e] = av[e] ? (short)f2bf(th) : (short)0;
        }
        return pk;
    };

    f32x4 acc[8];
    #pragma unroll
    for (int i = 0; i < 8; ++i) acc[i] = (f32x4){0.f, 0.f, 0.f, 0.f};

    auto mma8 = [&](short8 f0, short8 f1, const HbC& H) {
        #pragma unroll
        for (int tt = 0; tt < 8; ++tt)
            acc[tt] = __builtin_amdgcn_mfma_f32_16x16x32_bf16(
                f0, *(const short8*)&H.h[tt], acc[tt], 0, 0, 0);
        #pragma unroll
        for (int tt = 0; tt < 8; ++tt)
            acc[tt] = __builtin_amdgcn_mfma_f32_16x16x32_bf16(
                f1, *(const short8*)&H.h[8 + tt], acc[tt], 0, 0, 0);
    };

    // 2-deep adj/al prefetch; ht loaded per half-body (L2, covered by tanh VALU)
    AdjC aA = ld_adj(0), aB = ld_adj(1);
    AlC  lA = ld_al(0),  lB = ld_al(1);

    #pragma unroll 1
    for (int c = 0; c < 32; c += 2) {
        HbC hA = ld_hb(c);
        short8 f0 = alpha2(aA, lA, 0);
        short8 f1 = alpha2(aA, lA, 1);
        if (c + 2 < 32) { aA = ld_adj(c + 2); lA = ld_al(c + 2); }
        mma8(f0, f1, hA);

        HbC hB = ld_hb(c + 1);
        short8 g0 = alpha2(aB, lB, 0);
        short8 g1 = alpha2(aB, lB, 1);
        if (c + 3 < 32) { aB = ld_adj(c + 3); lB = ld_al(c + 3); }
        mma8(g0, g1, hB);
    }

    // ---- epilogue: out = acc + eps*x0 ----
    #pragma unroll
    for (int tt = 0; tt < 8; ++tt) {
        const int o = tt * 16 + lr;
        #pragma unroll
        for (int r = 0; r < 4; ++r) {
            const int row = i0 + q * 4 + r;
            const size_t idx = ((size_t)(b * N_) + row) * C_ + o;
            out[idx] = acc[tt][r] + EPS_ * x0[idx];
        }
    }
}

extern "C" void kernel_launch(void* const* d_in, const int* in_sizes, int n_in,
                              void* d_out, int out_size, void* d_ws, size_t ws_size,
                              hipStream_t stream) {
    const float* x   = (const float*)d_in[0];
    const float* x0  = (const float*)d_in[1];
    const int*   adj = (const int*)d_in[2];
    const float* W   = (const float*)d_in[3];
    const float* wl  = (const float*)d_in[4];
    const float* wr  = (const float*)d_in[5];
    float* out = (float*)d_out;

    unsigned short* ht = (unsigned short*)d_ws;                      // 4 MB
    float* al = (float*)((char*)d_ws + (size_t)B_ * C_ * N_ * 2);
    float* ar = al + B_ * N_;
    unsigned short* Wt = (unsigned short*)(ar + B_ * N_);            // 32 KB

    k_wt <<<C_,             C_,  0, stream>>>(W, Wt);
    k_h  <<<B_ * (N_ / 64), 256, 0, stream>>>(x, Wt, wl, wr, ht, al, ar);
    k_out<<<B_ * (N_ / 16), 64,  0, stream>>>(adj, ht, al, ar, x0, out);
}